// Round 1
// baseline (35381.924 us; speedup 1.0000x reference)
//
#include <hip/hip_runtime.h>
#include <hip/hip_cooperative_groups.h>

#define TT 512
#define BB 64
#define II 128
#define HH 1024
#define OO 128

typedef _Float16 half8 __attribute__((ext_vector_type(8)));
typedef float floatx4 __attribute__((ext_vector_type(4)));

__device__ __forceinline__ float sigm(float x){ return 1.0f/(1.0f + __expf(-x)); }

// ---------------- prep kernels ----------------
// X16[t][b][i] = fp16(inputs[b][t][i]); exact grid, no bounds check.
__global__ void prep_x_kernel(const float* __restrict__ x, _Float16* __restrict__ X16){
  int idx = blockIdx.x*256 + threadIdx.x;         // idx over [t][b][i]
  int i = idx & (II-1);
  int b = (idx >> 7) & (BB-1);
  int t = idx >> 13;
  X16[idx] = (_Float16)x[((size_t)b*TT + t)*II + i];
}

// W1cat [4096][1152] = [w_ih1 | w_hh1]; W2cat [4096][2048] = [w_ih2 | w_hh2];
// WL [128][1024]; zero both parities of H1/H2 state buffers.
__global__ void prep_w_kernel(const float* __restrict__ wih1, const float* __restrict__ whh1,
                              const float* __restrict__ wih2, const float* __restrict__ whh2,
                              const float* __restrict__ wlin,
                              _Float16* __restrict__ W1, _Float16* __restrict__ W2,
                              _Float16* __restrict__ WL, _Float16* __restrict__ H1,
                              _Float16* __restrict__ H2){
  long idx = (long)blockIdx.x*256 + threadIdx.x;
  const long n1 = 4096L*1152, n2 = 4096L*2048, nl = 128L*1024;
  if (idx < n1){
    int k = (int)(idx % 1152); int j = (int)(idx / 1152);
    W1[idx] = (_Float16)(k < II ? wih1[(size_t)j*II + k] : whh1[(size_t)j*HH + (k-II)]);
  } else if ((idx -= n1) < n2){
    int k = (int)(idx % 2048); int j = (int)(idx / 2048);
    W2[idx] = (_Float16)(k < HH ? wih2[(size_t)j*HH + k] : whh2[(size_t)j*HH + (k-HH)]);
  } else if ((idx -= n2) < nl){
    WL[idx] = (_Float16)wlin[idx];
  } else {
    idx -= nl;                                    // [0, 2*BB*HH)
    H1[idx] = (_Float16)0.0f;
    H2[idx] = (_Float16)0.0f;
  }
}

// ---------------- persistent pipelined LSTM ----------------
// Grid of 196 WGs x 256 threads, cooperative launch.
//   wg   0..63 : layer-1, 16 hidden units each (64x64 gate tile, K=1152)
//   wg  64..191: layer-2,  8 hidden units each (64x32 gate tile, K=2048)
//   wg 192..195: output projection, 32 cols each (64x32, K=1024)
// Interval s: L1 computes t=s, L2 computes t=s-1, Y computes t=s-2; grid.sync().
// h buffers double-buffered by t&1; c-states live in registers for all 512 steps.
__global__ void __launch_bounds__(256, 1)
lstm_persist_kernel(const _Float16* __restrict__ X16,
                    const _Float16* __restrict__ W1,
                    const _Float16* __restrict__ W2,
                    const _Float16* __restrict__ WL,
                    _Float16* __restrict__ H1,
                    _Float16* __restrict__ H2,
                    const float* __restrict__ bi1, const float* __restrict__ bh1,
                    const float* __restrict__ bi2, const float* __restrict__ bh2,
                    const float* __restrict__ blin,
                    float* __restrict__ out)
{
  auto grid = cooperative_groups::this_grid();
  const int wg   = blockIdx.x;
  const int tid  = threadIdx.x;
  const int wv   = tid >> 6;        // wave 0..3 -> batch rows 16*wv..+15
  const int lane = tid & 63;
  const int q    = lane >> 4;       // quad
  const int n    = lane & 15;
  const int mrow = wv << 4;
  const floatx4 zero4 = {0.f, 0.f, 0.f, 0.f};

  if (wg < 64){
    // ---------------- layer 1 ----------------
    const int j0 = wg << 4;
    const int j  = j0 + n;                         // this lane's hidden unit (B/C col)
    const _Float16* wrow[4];
    float bias[4];
#pragma unroll
    for (int g = 0; g < 4; ++g){
      wrow[g] = W1 + (size_t)(g*HH + j)*1152 + q*8;
      bias[g] = bi1[g*HH + j] + bh1[g*HH + j];
    }
    float c1s[4] = {0.f, 0.f, 0.f, 0.f};
    for (int s = 0; s < TT + 2; ++s){
      if (s < TT){
        const int t = s;
        floatx4 acc[4];
#pragma unroll
        for (int g = 0; g < 4; ++g) acc[g] = zero4;
        const _Float16* xb = X16 + (size_t)t*BB*II + (size_t)(mrow+n)*II + q*8;
        const _Float16* hb = H1 + (size_t)((t+1)&1)*BB*HH + (size_t)(mrow+n)*HH + q*8;
#pragma unroll
        for (int c = 0; c < 4; ++c){              // x part, K=128
          half8 a = *(const half8*)(xb + c*32);
#pragma unroll
          for (int g = 0; g < 4; ++g)
            acc[g] = __builtin_amdgcn_mfma_f32_16x16x32_f16(a, *(const half8*)(wrow[g] + c*32), acc[g], 0, 0, 0);
        }
#pragma unroll 4
        for (int c = 0; c < 32; ++c){             // h1 part, K=1024
          half8 a = *(const half8*)(hb + c*32);
#pragma unroll
          for (int g = 0; g < 4; ++g)
            acc[g] = __builtin_amdgcn_mfma_f32_16x16x32_f16(a, *(const half8*)(wrow[g] + (4+c)*32), acc[g], 0, 0, 0);
        }
        _Float16* ho = H1 + (size_t)(t&1)*BB*HH;
#pragma unroll
        for (int r = 0; r < 4; ++r){              // all 4 gates in-lane: i,f,g,o
          float gi = acc[0][r] + bias[0];
          float gf = acc[1][r] + bias[1];
          float gg = acc[2][r] + bias[2];
          float go = acc[3][r] + bias[3];
          float cc = sigm(gf)*c1s[r] + sigm(gi)*tanhf(gg);
          c1s[r] = cc;
          float h = sigm(go)*tanhf(cc);
          ho[(size_t)(mrow + q*4 + r)*HH + j] = (_Float16)h;
        }
      }
      __threadfence();
      grid.sync();
    }
  } else if (wg < 192){
    // ---------------- layer 2 ----------------
    const int j0 = (wg - 64) << 3;
    const int jj = j0 + (n & 7);
    // tile p cols: gate (p*2 + (n>>3)), unit j0+(n&7)
    const _Float16* wrow[2];
#pragma unroll
    for (int p = 0; p < 2; ++p)
      wrow[p] = W2 + (size_t)((p*2 + (n>>3))*HH + jj)*2048 + q*8;
    float bias[4];
#pragma unroll
    for (int g = 0; g < 4; ++g) bias[g] = bi2[g*HH + jj] + bh2[g*HH + jj];
    float c2s[2] = {0.f, 0.f};
    const int rbase = (n < 8) ? 0 : 2;
    for (int s = 0; s < TT + 2; ++s){
      if (s >= 1 && s <= TT){
        const int t = s - 1;
        floatx4 acc[2];
        acc[0] = zero4; acc[1] = zero4;
        const _Float16* a1 = H1 + (size_t)(t&1)*BB*HH + (size_t)(mrow+n)*HH + q*8;
        const _Float16* a2 = H2 + (size_t)((t+1)&1)*BB*HH + (size_t)(mrow+n)*HH + q*8;
#pragma unroll 8
        for (int c = 0; c < 32; ++c){             // h1_t part
          half8 a = *(const half8*)(a1 + c*32);
          acc[0] = __builtin_amdgcn_mfma_f32_16x16x32_f16(a, *(const half8*)(wrow[0] + c*32), acc[0], 0, 0, 0);
          acc[1] = __builtin_amdgcn_mfma_f32_16x16x32_f16(a, *(const half8*)(wrow[1] + c*32), acc[1], 0, 0, 0);
        }
#pragma unroll 8
        for (int c = 0; c < 32; ++c){             // h2_{t-1} part
          half8 a = *(const half8*)(a2 + c*32);
          acc[0] = __builtin_amdgcn_mfma_f32_16x16x32_f16(a, *(const half8*)(wrow[0] + (32+c)*32), acc[0], 0, 0, 0);
          acc[1] = __builtin_amdgcn_mfma_f32_16x16x32_f16(a, *(const half8*)(wrow[1] + (32+c)*32), acc[1], 0, 0, 0);
        }
        // gather i,f,g,o per (b, jj) via xor-8 shuffle: lane n<8 holds (i,g), n>=8 holds (f,o)
        float vi[4], vf[4], vg[4], vo[4];
#pragma unroll
        for (int r = 0; r < 4; ++r){
          float p0 = acc[0][r], p1 = acc[1][r];
          float s0 = __shfl_xor(p0, 8, 64);
          float s1 = __shfl_xor(p1, 8, 64);
          vi[r] = (n < 8) ? p0 : s0;
          vf[r] = (n < 8) ? s0 : p0;
          vg[r] = (n < 8) ? p1 : s1;
          vo[r] = (n < 8) ? s1 : p1;
        }
        _Float16* ho = H2 + (size_t)(t&1)*BB*HH;
#pragma unroll
        for (int rr = 0; rr < 2; ++rr){           // each lane updates 2 rows of its unit
          int r = rbase + rr;
          float gi = vi[r] + bias[0];
          float gf = vf[r] + bias[1];
          float gg = vg[r] + bias[2];
          float go = vo[r] + bias[3];
          float cc = sigm(gf)*c2s[rr] + sigm(gi)*tanhf(gg);
          c2s[rr] = cc;
          float h = sigm(go)*tanhf(cc);
          ho[(size_t)(mrow + q*4 + r)*HH + jj] = (_Float16)h;
        }
      }
      __threadfence();
      grid.sync();
    }
  } else {
    // ---------------- output projection ----------------
    const int j0 = (wg - 192) << 5;
    const _Float16* wrow[2];
    float by[2];
#pragma unroll
    for (int p = 0; p < 2; ++p){
      wrow[p] = WL + (size_t)(j0 + p*16 + n)*HH + q*8;
      by[p] = blin[j0 + p*16 + n];
    }
    for (int s = 0; s < TT + 2; ++s){
      if (s >= 2){
        const int t = s - 2;
        floatx4 acc[2];
        acc[0] = zero4; acc[1] = zero4;
        const _Float16* a2 = H2 + (size_t)(t&1)*BB*HH + (size_t)(mrow+n)*HH + q*8;
#pragma unroll 8
        for (int c = 0; c < 32; ++c){
          half8 a = *(const half8*)(a2 + c*32);
          acc[0] = __builtin_amdgcn_mfma_f32_16x16x32_f16(a, *(const half8*)(wrow[0] + c*32), acc[0], 0, 0, 0);
          acc[1] = __builtin_amdgcn_mfma_f32_16x16x32_f16(a, *(const half8*)(wrow[1] + c*32), acc[1], 0, 0, 0);
        }
#pragma unroll
        for (int p = 0; p < 2; ++p){
          int col = j0 + p*16 + n;
#pragma unroll
          for (int r = 0; r < 4; ++r){
            int b = mrow + q*4 + r;
            out[((size_t)b*TT + t)*OO + col] = acc[p][r] + by[p];
          }
        }
      }
      __threadfence();
      grid.sync();
    }
  }
}

// ---------------- launch ----------------
extern "C" void kernel_launch(void* const* d_in, const int* in_sizes, int n_in,
                              void* d_out, int out_size, void* d_ws, size_t ws_size,
                              hipStream_t stream){
  const float* x    = (const float*)d_in[0];
  const float* wih1 = (const float*)d_in[1];
  const float* whh1 = (const float*)d_in[2];
  const float* bi1  = (const float*)d_in[3];
  const float* bh1  = (const float*)d_in[4];
  const float* wih2 = (const float*)d_in[5];
  const float* whh2 = (const float*)d_in[6];
  const float* bi2  = (const float*)d_in[7];
  const float* bh2  = (const float*)d_in[8];
  const float* wlin = (const float*)d_in[9];
  const float* blin = (const float*)d_in[10];
  float* out = (float*)d_out;

  // workspace carve (bytes, 256-aligned):
  char* ws = (char*)d_ws;
  _Float16* X16 = (_Float16*)(ws + 0);          //  8,388,608  [512][64][128]
  _Float16* W1  = (_Float16*)(ws + 8388608);    //  9,437,184  [4096][1152]
  _Float16* W2  = (_Float16*)(ws + 17825792);   // 16,777,216  [4096][2048]
  _Float16* WL  = (_Float16*)(ws + 34603008);   //    262,144  [128][1024]
  _Float16* H1  = (_Float16*)(ws + 34865152);   //    262,144  [2][64][1024]
  _Float16* H2  = (_Float16*)(ws + 35127296);   //    262,144  [2][64][1024]
  // total 35,389,440 bytes

  prep_x_kernel<<<dim3(16384), dim3(256), 0, stream>>>(x, X16);
  prep_w_kernel<<<dim3(52224), dim3(256), 0, stream>>>(wih1, whh1, wih2, whh2, wlin,
                                                       W1, W2, WL, H1, H2);

  void* args[] = {(void*)&X16, (void*)&W1, (void*)&W2, (void*)&WL, (void*)&H1, (void*)&H2,
                  (void*)&bi1, (void*)&bh1, (void*)&bi2, (void*)&bh2, (void*)&blin,
                  (void*)&out};
  hipLaunchCooperativeKernel((const void*)lstm_persist_kernel, dim3(196), dim3(256),
                             args, 0, stream);
}

// Round 4
// 33919.757 us; speedup vs baseline: 1.0431x; 1.0431x over previous
//
#include <hip/hip_runtime.h>
#include <hip/hip_cooperative_groups.h>

#define TT 512
#define BB 64
#define II 128
#define HH 1024
#define OO 128
#define NWG 196

typedef _Float16 half8 __attribute__((ext_vector_type(8)));
typedef float floatx4 __attribute__((ext_vector_type(4)));

__device__ __forceinline__ float sigm(float x){ return 1.0f/(1.0f + __expf(-x)); }

// ---------------- prep kernels (verbatim from passing round 1) ----------------
__global__ void prep_x_kernel(const float* __restrict__ x, _Float16* __restrict__ X16){
  int idx = blockIdx.x*256 + threadIdx.x;         // idx over [t][b][i]
  int i = idx & (II-1);
  int b = (idx >> 7) & (BB-1);
  int t = idx >> 13;
  X16[idx] = (_Float16)x[((size_t)b*TT + t)*II + i];
}

__global__ void prep_w_kernel(const float* __restrict__ wih1, const float* __restrict__ whh1,
                              const float* __restrict__ wih2, const float* __restrict__ whh2,
                              const float* __restrict__ wlin,
                              _Float16* __restrict__ W1, _Float16* __restrict__ W2,
                              _Float16* __restrict__ WL, _Float16* __restrict__ H1,
                              _Float16* __restrict__ H2){
  long idx = (long)blockIdx.x*256 + threadIdx.x;
  const long n1 = 4096L*1152, n2 = 4096L*2048, nl = 128L*1024;
  if (idx < n1){
    int k = (int)(idx % 1152); int j = (int)(idx / 1152);
    W1[idx] = (_Float16)(k < II ? wih1[(size_t)j*II + k] : whh1[(size_t)j*HH + (k-II)]);
  } else if ((idx -= n1) < n2){
    int k = (int)(idx % 2048); int j = (int)(idx / 2048);
    W2[idx] = (_Float16)(k < HH ? wih2[(size_t)j*HH + k] : whh2[(size_t)j*HH + (k-HH)]);
  } else if ((idx -= n2) < nl){
    WL[idx] = (_Float16)wlin[idx];
  } else {
    idx -= nl;                                    // [0, 2*BB*HH)
    H1[idx] = (_Float16)0.0f;
    H2[idx] = (_Float16)0.0f;
  }
}

// ---------------- persistent pipelined LSTM ----------------
// 196 WGs x 256 thr, CG cooperative launch (proven path).
//   wg   0..63 : layer-1, 16 units (64x64 gate tile, K=1152)
//   wg  64..191: layer-2,  8 units (64x32 gate tile, K=2048)
//   wg 192..195: output projection, 32 cols (64x32, K=1024)
// Interval s: L1 t=s, L2 t=s-1, Y t=s-2; grid.sync() between intervals.
// Loads are batched into explicit register arrays to force deep vmem
// pipelining (round-1 had VGPR=56 -> ~2-3 loads in flight -> latency-bound).
__global__ void __launch_bounds__(256, 1)
lstm_persist_kernel(const _Float16* __restrict__ X16,
                    const _Float16* __restrict__ W1,
                    const _Float16* __restrict__ W2,
                    const _Float16* __restrict__ WL,
                    _Float16* __restrict__ H1,
                    _Float16* __restrict__ H2,
                    const float* __restrict__ bi1, const float* __restrict__ bh1,
                    const float* __restrict__ bi2, const float* __restrict__ bh2,
                    const float* __restrict__ blin,
                    float* __restrict__ out)
{
  auto grid = cooperative_groups::this_grid();
  const int wg   = blockIdx.x;
  const int tid  = threadIdx.x;
  const int wv   = tid >> 6;
  const int lane = tid & 63;
  const int q    = lane >> 4;
  const int n    = lane & 15;
  const int mrow = wv << 4;
  const floatx4 zero4 = {0.f, 0.f, 0.f, 0.f};

  if (wg < 64){
    // ---------------- layer 1 ----------------
    const int j0 = wg << 4;
    const int j  = j0 + n;
    const _Float16* wrow[4];
    float bias[4];
#pragma unroll
    for (int g = 0; g < 4; ++g){
      wrow[g] = W1 + (size_t)(g*HH + j)*1152 + q*8;
      bias[g] = bi1[g*HH + j] + bh1[g*HH + j];
    }
    // x-part weights are loop-invariant: keep in registers for all 512 steps
    half8 Wx[4][4];
#pragma unroll
    for (int g = 0; g < 4; ++g)
#pragma unroll
      for (int c = 0; c < 4; ++c)
        Wx[g][c] = *(const half8*)(wrow[g] + c*32);

    float c1s[4] = {0.f, 0.f, 0.f, 0.f};
    for (int s = 0; s < TT + 2; ++s){
      if (s < TT){
        const int t = s;
        const _Float16* xb = X16 + ((size_t)t*BB + (mrow+n))*II + q*8;
        const _Float16* hb = H1 + ((size_t)((t+1)&1)*BB + (mrow+n))*HH + q*8;
        // batch-issue x + h fragment loads (independent -> deep in flight)
        half8 xf[4];
#pragma unroll
        for (int c = 0; c < 4; ++c) xf[c] = *(const half8*)(xb + c*32);
        half8 hA[32];
#pragma unroll
        for (int c = 0; c < 32; ++c) hA[c] = *(const half8*)(hb + c*32);

        floatx4 acc[4];
#pragma unroll
        for (int g = 0; g < 4; ++g) acc[g] = zero4;
        // x-part MFMAs run while hA / gate-0 weights arrive
#pragma unroll
        for (int c = 0; c < 4; ++c)
#pragma unroll
          for (int g = 0; g < 4; ++g)
            acc[g] = __builtin_amdgcn_mfma_f32_16x16x32_f16(xf[c], Wx[g][c], acc[g], 0, 0, 0);
        // h-part: stream weights one gate at a time through a 32-frag buffer
#pragma unroll
        for (int g = 0; g < 4; ++g){
          half8 Wb[32];
#pragma unroll
          for (int c = 0; c < 32; ++c) Wb[c] = *(const half8*)(wrow[g] + (4+c)*32);
#pragma unroll
          for (int c = 0; c < 32; ++c)
            acc[g] = __builtin_amdgcn_mfma_f32_16x16x32_f16(hA[c], Wb[c], acc[g], 0, 0, 0);
        }
        _Float16* ho = H1 + (size_t)(t&1)*BB*HH;
#pragma unroll
        for (int r = 0; r < 4; ++r){
          float gi = acc[0][r] + bias[0];
          float gf = acc[1][r] + bias[1];
          float gg = acc[2][r] + bias[2];
          float go = acc[3][r] + bias[3];
          float cc = sigm(gf)*c1s[r] + sigm(gi)*tanhf(gg);
          c1s[r] = cc;
          float h = sigm(go)*tanhf(cc);
          ho[(size_t)(mrow + q*4 + r)*HH + j] = (_Float16)h;
        }
      }
      __threadfence();
      grid.sync();
    }
  } else if (wg < 192){
    // ---------------- layer 2 ----------------
    const int j0 = (wg - 64) << 3;
    const int jj = j0 + (n & 7);
    const _Float16* wrow[2];
#pragma unroll
    for (int p = 0; p < 2; ++p)
      wrow[p] = W2 + (size_t)((p*2 + (n>>3))*HH + jj)*2048 + q*8;
    float bias[4];
#pragma unroll
    for (int g = 0; g < 4; ++g) bias[g] = bi2[g*HH + jj] + bh2[g*HH + jj];
    float c2s[2] = {0.f, 0.f};
    const int rbase = (n < 8) ? 0 : 2;
    for (int s = 0; s < TT + 2; ++s){
      if (s >= 1 && s <= TT){
        const int t = s - 1;
        const _Float16* a1 = H1 + ((size_t)(t&1)*BB + (mrow+n))*HH + q*8;
        const _Float16* a2 = H2 + ((size_t)((t+1)&1)*BB + (mrow+n))*HH + q*8;
        half8 hA1[32];
#pragma unroll
        for (int c = 0; c < 32; ++c) hA1[c] = *(const half8*)(a1 + c*32);
        half8 hA2[32];
#pragma unroll
        for (int c = 0; c < 32; ++c) hA2[c] = *(const half8*)(a2 + c*32);

        floatx4 acc[2];
        acc[0] = zero4; acc[1] = zero4;
#pragma unroll
        for (int p = 0; p < 2; ++p){
          half8 Wb[32];
#pragma unroll
          for (int c = 0; c < 32; ++c) Wb[c] = *(const half8*)(wrow[p] + c*32);
#pragma unroll
          for (int c = 0; c < 32; ++c)
            acc[p] = __builtin_amdgcn_mfma_f32_16x16x32_f16(hA1[c], Wb[c], acc[p], 0, 0, 0);
#pragma unroll
          for (int c = 0; c < 32; ++c) Wb[c] = *(const half8*)(wrow[p] + (32+c)*32);
#pragma unroll
          for (int c = 0; c < 32; ++c)
            acc[p] = __builtin_amdgcn_mfma_f32_16x16x32_f16(hA2[c], Wb[c], acc[p], 0, 0, 0);
        }
        float vi[4], vf[4], vg[4], vo[4];
#pragma unroll
        for (int r = 0; r < 4; ++r){
          float p0 = acc[0][r], p1 = acc[1][r];
          float s0 = __shfl_xor(p0, 8, 64);
          float s1 = __shfl_xor(p1, 8, 64);
          vi[r] = (n < 8) ? p0 : s0;
          vf[r] = (n < 8) ? s0 : p0;
          vg[r] = (n < 8) ? p1 : s1;
          vo[r] = (n < 8) ? s1 : p1;
        }
        _Float16* ho = H2 + (size_t)(t&1)*BB*HH;
#pragma unroll
        for (int rr = 0; rr < 2; ++rr){
          int r = rbase + rr;
          float gi = vi[r] + bias[0];
          float gf = vf[r] + bias[1];
          float gg = vg[r] + bias[2];
          float go = vo[r] + bias[3];
          float cc = sigm(gf)*c2s[rr] + sigm(gi)*tanhf(gg);
          c2s[rr] = cc;
          float h = sigm(go)*tanhf(cc);
          ho[(size_t)(mrow + q*4 + r)*HH + jj] = (_Float16)h;
        }
      }
      __threadfence();
      grid.sync();
    }
  } else {
    // ---------------- output projection ----------------
    const int j0 = (wg - 192) << 5;
    const _Float16* wrow[2];
    float by[2];
#pragma unroll
    for (int p = 0; p < 2; ++p){
      wrow[p] = WL + (size_t)(j0 + p*16 + n)*HH + q*8;
      by[p] = blin[j0 + p*16 + n];
    }
    for (int s = 0; s < TT + 2; ++s){
      if (s >= 2){
        const int t = s - 2;
        const _Float16* a2 = H2 + ((size_t)(t&1)*BB + (mrow+n))*HH + q*8;
        half8 hA[32];
#pragma unroll
        for (int c = 0; c < 32; ++c) hA[c] = *(const half8*)(a2 + c*32);
        floatx4 acc[2];
        acc[0] = zero4; acc[1] = zero4;
#pragma unroll
        for (int p = 0; p < 2; ++p){
          half8 Wb[32];
#pragma unroll
          for (int c = 0; c < 32; ++c) Wb[c] = *(const half8*)(wrow[p] + c*32);
#pragma unroll
          for (int c = 0; c < 32; ++c)
            acc[p] = __builtin_amdgcn_mfma_f32_16x16x32_f16(hA[c], Wb[c], acc[p], 0, 0, 0);
        }
#pragma unroll
        for (int p = 0; p < 2; ++p){
          int col = j0 + p*16 + n;
#pragma unroll
          for (int r = 0; r < 4; ++r){
            int b = mrow + q*4 + r;
            out[((size_t)b*TT + t)*OO + col] = acc[p][r] + by[p];
          }
        }
      }
      __threadfence();
      grid.sync();
    }
  }
}

// ---------------- launch ----------------
extern "C" void kernel_launch(void* const* d_in, const int* in_sizes, int n_in,
                              void* d_out, int out_size, void* d_ws, size_t ws_size,
                              hipStream_t stream){
  const float* x    = (const float*)d_in[0];
  const float* wih1 = (const float*)d_in[1];
  const float* whh1 = (const float*)d_in[2];
  const float* bi1  = (const float*)d_in[3];
  const float* bh1  = (const float*)d_in[4];
  const float* wih2 = (const float*)d_in[5];
  const float* whh2 = (const float*)d_in[6];
  const float* bi2  = (const float*)d_in[7];
  const float* bh2  = (const float*)d_in[8];
  const float* wlin = (const float*)d_in[9];
  const float* blin = (const float*)d_in[10];
  float* out = (float*)d_out;

  char* ws = (char*)d_ws;
  _Float16* X16 = (_Float16*)(ws + 0);          //  8,388,608  [512][64][128]
  _Float16* W1  = (_Float16*)(ws + 8388608);    //  9,437,184  [4096][1152]
  _Float16* W2  = (_Float16*)(ws + 17825792);   // 16,777,216  [4096][2048]
  _Float16* WL  = (_Float16*)(ws + 34603008);   //    262,144  [128][1024]
  _Float16* H1  = (_Float16*)(ws + 34865152);   //    262,144  [2][64][1024]
  _Float16* H2  = (_Float16*)(ws + 35127296);   //    262,144  [2][64][1024]

  prep_x_kernel<<<dim3(16384), dim3(256), 0, stream>>>(x, X16);
  prep_w_kernel<<<dim3(52224), dim3(256), 0, stream>>>(wih1, whh1, wih2, whh2, wlin,
                                                       W1, W2, WL, H1, H2);

  void* args[] = {(void*)&X16, (void*)&W1, (void*)&W2, (void*)&WL, (void*)&H1, (void*)&H2,
                  (void*)&bi1, (void*)&bh1, (void*)&bi2, (void*)&bh2, (void*)&blin,
                  (void*)&out};
  hipLaunchCooperativeKernel((const void*)lstm_persist_kernel, dim3(NWG), dim3(256),
                             args, 0, stream);
}

// Round 6
// 12492.216 us; speedup vs baseline: 2.8323x; 2.7153x over previous
//
#include <hip/hip_runtime.h>

#define TT 512
#define BB 64
#define II 128
#define HH 1024
#define OO 128
#define NWG 196

typedef _Float16 half8 __attribute__((ext_vector_type(8)));
typedef float floatx4 __attribute__((ext_vector_type(4)));

__device__ __forceinline__ float sigm(float x){ return 1.0f/(1.0f + __expf(-x)); }

// ---------------- prep kernels (verbatim from passing rounds 1/4) ----------------
__global__ void prep_x_kernel(const float* __restrict__ x, _Float16* __restrict__ X16){
  int idx = blockIdx.x*256 + threadIdx.x;         // idx over [t][b][i]
  int i = idx & (II-1);
  int b = (idx >> 7) & (BB-1);
  int t = idx >> 13;
  X16[idx] = (_Float16)x[((size_t)b*TT + t)*II + i];
}

__global__ void prep_w_kernel(const float* __restrict__ wih1, const float* __restrict__ whh1,
                              const float* __restrict__ wih2, const float* __restrict__ whh2,
                              const float* __restrict__ wlin,
                              _Float16* __restrict__ W1, _Float16* __restrict__ W2,
                              _Float16* __restrict__ WL, _Float16* __restrict__ H1,
                              _Float16* __restrict__ H2){
  long idx = (long)blockIdx.x*256 + threadIdx.x;
  const long n1 = 4096L*1152, n2 = 4096L*2048, nl = 128L*1024;
  if (idx < n1){
    int k = (int)(idx % 1152); int j = (int)(idx / 1152);
    W1[idx] = (_Float16)(k < II ? wih1[(size_t)j*II + k] : whh1[(size_t)j*HH + (k-II)]);
  } else if ((idx -= n1) < n2){
    int k = (int)(idx % 2048); int j = (int)(idx / 2048);
    W2[idx] = (_Float16)(k < HH ? wih2[(size_t)j*HH + k] : whh2[(size_t)j*HH + (k-HH)]);
  } else if ((idx -= n2) < nl){
    WL[idx] = (_Float16)wlin[idx];
  } else {
    idx -= nl;                                    // [0, 2*BB*HH)
    H1[idx] = (_Float16)0.0f;
    H2[idx] = (_Float16)0.0f;
  }
}

// ---------------- one pipeline interval per dispatch ----------------
// Normal (non-cooperative) launch, 196 WGs x 256 thr. The kernel boundary IS
// the grid barrier (AQL release/acquire: device-visible, proven semantics).
//   wg   0..63 : layer-1 step t=s      (16 units, 64x64 gate tile, K=1152)
//   wg  64..191: layer-2 step t=s-1    ( 8 units, 64x32 gate tile, K=2048)
//   wg 192..195: projection step t=s-2 (32 cols,  64x32,          K=1024)
// Cell states c1/c2 persist in global fp32 buffers (C1S/C2S) across dispatches.
// Math is bit-identical to the passing round-4 kernel (absmax 1.95e-3).
__global__ void __launch_bounds__(256, 1)
lstm_step_kernel(const _Float16* __restrict__ X16,
                 const _Float16* __restrict__ W1,
                 const _Float16* __restrict__ W2,
                 const _Float16* __restrict__ WL,
                 _Float16* __restrict__ H1,
                 _Float16* __restrict__ H2,
                 float* __restrict__ C1S,
                 float* __restrict__ C2S,
                 const float* __restrict__ bi1, const float* __restrict__ bh1,
                 const float* __restrict__ bi2, const float* __restrict__ bh2,
                 const float* __restrict__ blin,
                 float* __restrict__ out,
                 int s)
{
  const int wg   = blockIdx.x;
  const int tid  = threadIdx.x;
  const int wv   = tid >> 6;
  const int lane = tid & 63;
  const int q    = lane >> 4;
  const int n    = lane & 15;
  const int mrow = wv << 4;
  const floatx4 zero4 = {0.f, 0.f, 0.f, 0.f};

  if (wg < 64){
    // ---------------- layer 1, t = s ----------------
    if (s >= TT) return;
    const int t = s;
    const int j0 = wg << 4;
    const int j  = j0 + n;
    const _Float16* wrow[4];
    float bias[4];
#pragma unroll
    for (int g = 0; g < 4; ++g){
      wrow[g] = W1 + (size_t)(g*HH + j)*1152 + q*8;
      bias[g] = bi1[g*HH + j] + bh1[g*HH + j];
    }
    const _Float16* xb = X16 + ((size_t)t*BB + (mrow+n))*II + q*8;
    const _Float16* hb = H1 + ((size_t)((t+1)&1)*BB + (mrow+n))*HH + q*8;
    // batch-issue x + h fragment loads (independent -> deep in flight)
    half8 xf[4];
#pragma unroll
    for (int c = 0; c < 4; ++c) xf[c] = *(const half8*)(xb + c*32);
    half8 hA[32];
#pragma unroll
    for (int c = 0; c < 32; ++c) hA[c] = *(const half8*)(hb + c*32);
    half8 Wx[4][4];
#pragma unroll
    for (int g = 0; g < 4; ++g)
#pragma unroll
      for (int c = 0; c < 4; ++c)
        Wx[g][c] = *(const half8*)(wrow[g] + c*32);

    floatx4 acc[4];
#pragma unroll
    for (int g = 0; g < 4; ++g) acc[g] = zero4;
#pragma unroll
    for (int c = 0; c < 4; ++c)
#pragma unroll
      for (int g = 0; g < 4; ++g)
        acc[g] = __builtin_amdgcn_mfma_f32_16x16x32_f16(xf[c], Wx[g][c], acc[g], 0, 0, 0);
#pragma unroll
    for (int g = 0; g < 4; ++g){
      half8 Wb[32];
#pragma unroll
      for (int c = 0; c < 32; ++c) Wb[c] = *(const half8*)(wrow[g] + (4+c)*32);
#pragma unroll
      for (int c = 0; c < 32; ++c)
        acc[g] = __builtin_amdgcn_mfma_f32_16x16x32_f16(hA[c], Wb[c], acc[g], 0, 0, 0);
    }
    // cell state: [b][j] fp32, laid out per-lane: idx = b*HH + j
    _Float16* ho = H1 + (size_t)(t&1)*BB*HH;
#pragma unroll
    for (int r = 0; r < 4; ++r){
      const int b = mrow + q*4 + r;
      float cprev = C1S[(size_t)b*HH + j];
      float gi = acc[0][r] + bias[0];
      float gf = acc[1][r] + bias[1];
      float gg = acc[2][r] + bias[2];
      float go = acc[3][r] + bias[3];
      float cc = sigm(gf)*cprev + sigm(gi)*tanhf(gg);
      C1S[(size_t)b*HH + j] = cc;
      float h = sigm(go)*tanhf(cc);
      ho[(size_t)b*HH + j] = (_Float16)h;
    }
  } else if (wg < 192){
    // ---------------- layer 2, t = s-1 ----------------
    if (s < 1 || s > TT) return;
    const int t = s - 1;
    const int j0 = (wg - 64) << 3;
    const int jj = j0 + (n & 7);
    const _Float16* wrow[2];
#pragma unroll
    for (int p = 0; p < 2; ++p)
      wrow[p] = W2 + (size_t)((p*2 + (n>>3))*HH + jj)*2048 + q*8;
    float bias[4];
#pragma unroll
    for (int g = 0; g < 4; ++g) bias[g] = bi2[g*HH + jj] + bh2[g*HH + jj];
    const int rbase = (n < 8) ? 0 : 2;

    const _Float16* a1 = H1 + ((size_t)(t&1)*BB + (mrow+n))*HH + q*8;
    const _Float16* a2 = H2 + ((size_t)((t+1)&1)*BB + (mrow+n))*HH + q*8;
    half8 hA1[32];
#pragma unroll
    for (int c = 0; c < 32; ++c) hA1[c] = *(const half8*)(a1 + c*32);
    half8 hA2[32];
#pragma unroll
    for (int c = 0; c < 32; ++c) hA2[c] = *(const half8*)(a2 + c*32);

    floatx4 acc[2];
    acc[0] = zero4; acc[1] = zero4;
#pragma unroll
    for (int p = 0; p < 2; ++p){
      half8 Wb[32];
#pragma unroll
      for (int c = 0; c < 32; ++c) Wb[c] = *(const half8*)(wrow[p] + c*32);
#pragma unroll
      for (int c = 0; c < 32; ++c)
        acc[p] = __builtin_amdgcn_mfma_f32_16x16x32_f16(hA1[c], Wb[c], acc[p], 0, 0, 0);
#pragma unroll
      for (int c = 0; c < 32; ++c) Wb[c] = *(const half8*)(wrow[p] + (32+c)*32);
#pragma unroll
      for (int c = 0; c < 32; ++c)
        acc[p] = __builtin_amdgcn_mfma_f32_16x16x32_f16(hA2[c], Wb[c], acc[p], 0, 0, 0);
    }
    // gather i,f,g,o per (b,jj): lanes n<8 hold (i,g), n>=8 hold (f,o)
    float vi[4], vf[4], vg[4], vo[4];
#pragma unroll
    for (int r = 0; r < 4; ++r){
      float p0 = acc[0][r], p1 = acc[1][r];
      float s0 = __shfl_xor(p0, 8, 64);
      float s1 = __shfl_xor(p1, 8, 64);
      vi[r] = (n < 8) ? p0 : s0;
      vf[r] = (n < 8) ? s0 : p0;
      vg[r] = (n < 8) ? p1 : s1;
      vo[r] = (n < 8) ? s1 : p1;
    }
    _Float16* ho = H2 + (size_t)(t&1)*BB*HH;
#pragma unroll
    for (int rr = 0; rr < 2; ++rr){
      int r = rbase + rr;
      const int b = mrow + q*4 + r;
      float cprev = C2S[(size_t)b*HH + jj];
      float gi = vi[r] + bias[0];
      float gf = vf[r] + bias[1];
      float gg = vg[r] + bias[2];
      float go = vo[r] + bias[3];
      float cc = sigm(gf)*cprev + sigm(gi)*tanhf(gg);
      C2S[(size_t)b*HH + jj] = cc;
      float h = sigm(go)*tanhf(cc);
      ho[(size_t)b*HH + jj] = (_Float16)h;
    }
  } else {
    // ---------------- output projection, t = s-2 ----------------
    if (s < 2) return;
    const int t = s - 2;
    const int j0 = (wg - 192) << 5;
    const _Float16* wrow[2];
    float by[2];
#pragma unroll
    for (int p = 0; p < 2; ++p){
      wrow[p] = WL + (size_t)(j0 + p*16 + n)*HH + q*8;
      by[p] = blin[j0 + p*16 + n];
    }
    const _Float16* a2 = H2 + ((size_t)(t&1)*BB + (mrow+n))*HH + q*8;
    half8 hA[32];
#pragma unroll
    for (int c = 0; c < 32; ++c) hA[c] = *(const half8*)(a2 + c*32);
    floatx4 acc[2];
    acc[0] = zero4; acc[1] = zero4;
#pragma unroll
    for (int p = 0; p < 2; ++p){
      half8 Wb[32];
#pragma unroll
      for (int c = 0; c < 32; ++c) Wb[c] = *(const half8*)(wrow[p] + c*32);
#pragma unroll
      for (int c = 0; c < 32; ++c)
        acc[p] = __builtin_amdgcn_mfma_f32_16x16x32_f16(hA[c], Wb[c], acc[p], 0, 0, 0);
    }
#pragma unroll
    for (int p = 0; p < 2; ++p){
      int col = j0 + p*16 + n;
#pragma unroll
      for (int r = 0; r < 4; ++r){
        int b = mrow + q*4 + r;
        out[((size_t)b*TT + t)*OO + col] = acc[p][r] + by[p];
      }
    }
  }
}

// zero the fp32 cell-state buffers (ws is poisoned 0xAA before every call)
__global__ void prep_c_kernel(float* __restrict__ C1S, float* __restrict__ C2S){
  int idx = blockIdx.x*256 + threadIdx.x;   // 0 .. BB*HH-1
  C1S[idx] = 0.0f;
  C2S[idx] = 0.0f;
}

// ---------------- launch ----------------
extern "C" void kernel_launch(void* const* d_in, const int* in_sizes, int n_in,
                              void* d_out, int out_size, void* d_ws, size_t ws_size,
                              hipStream_t stream){
  const float* x    = (const float*)d_in[0];
  const float* wih1 = (const float*)d_in[1];
  const float* whh1 = (const float*)d_in[2];
  const float* bi1  = (const float*)d_in[3];
  const float* bh1  = (const float*)d_in[4];
  const float* wih2 = (const float*)d_in[5];
  const float* whh2 = (const float*)d_in[6];
  const float* bi2  = (const float*)d_in[7];
  const float* bh2  = (const float*)d_in[8];
  const float* wlin = (const float*)d_in[9];
  const float* blin = (const float*)d_in[10];
  float* out = (float*)d_out;

  char* ws = (char*)d_ws;
  _Float16* X16 = (_Float16*)(ws + 0);          //  8,388,608  [512][64][128]
  _Float16* W1  = (_Float16*)(ws + 8388608);    //  9,437,184  [4096][1152]
  _Float16* W2  = (_Float16*)(ws + 17825792);   // 16,777,216  [4096][2048]
  _Float16* WL  = (_Float16*)(ws + 34603008);   //    262,144  [128][1024]
  _Float16* H1  = (_Float16*)(ws + 34865152);   //    262,144  [2][64][1024]
  _Float16* H2  = (_Float16*)(ws + 35127296);   //    262,144  [2][64][1024]
  float*    C1S = (float*)(ws + 35389440);      //    262,144  [64][1024] fp32
  float*    C2S = (float*)(ws + 35651584);      //    262,144  [64][1024] fp32
  // total 35,913,728 bytes

  prep_x_kernel<<<dim3(16384), dim3(256), 0, stream>>>(x, X16);
  prep_w_kernel<<<dim3(52224), dim3(256), 0, stream>>>(wih1, whh1, wih2, whh2, wlin,
                                                       W1, W2, WL, H1, H2);
  prep_c_kernel<<<dim3(256), dim3(256), 0, stream>>>(C1S, C2S);

  // one dispatch per pipeline interval; kernel boundary = grid-wide barrier
  for (int s = 0; s < TT + 2; ++s){
    lstm_step_kernel<<<dim3(NWG), dim3(256), 0, stream>>>(
        X16, W1, W2, WL, H1, H2, C1S, C2S,
        bi1, bh1, bi2, bh2, blin, out, s);
  }
}